// Round 1
// baseline (574.175 us; speedup 1.0000x reference)
//
#include <hip/hip_runtime.h>
#include <cmath>

// ---------------------------------------------------------------------------
// GEMM: out[M,N] = A[M,K] @ W[N,K]^T + bias[N]   (torch Linear, NT layout)
// 128x128 tile, BK=16, 256 threads, 8x8 per thread as 2x2 quadrants of 4x4.
// Frag reads at t*4 and t*4+64 -> <=2-way LDS bank aliasing (free on gfx950).
// ---------------------------------------------------------------------------
#define TILE_M 128
#define TILE_N 128
#define TILE_K 16

__global__ __launch_bounds__(256) void gemm_bias_nt(
    const float* __restrict__ A,
    const float* __restrict__ W,
    const float* __restrict__ bias,
    float* __restrict__ out,
    int M, int N, int K)
{
    __shared__ __align__(16) float As[TILE_K][TILE_M + 4];
    __shared__ __align__(16) float Ws[TILE_K][TILE_N + 4];

    const int tid = threadIdx.x;
    const int tx = tid & 15;   // col group
    const int ty = tid >> 4;   // row group
    const int bm = blockIdx.y * TILE_M;
    const int bn = blockIdx.x * TILE_N;

    float acc[2][2][4][4];
#pragma unroll
    for (int a = 0; a < 2; ++a)
#pragma unroll
        for (int b = 0; b < 2; ++b)
#pragma unroll
            for (int i = 0; i < 4; ++i)
#pragma unroll
                for (int j = 0; j < 4; ++j)
                    acc[a][b][i][j] = 0.f;

    for (int k0 = 0; k0 < K; k0 += TILE_K) {
        // stage A and W tiles (transposed: [k][m]) — 2 float4 each per thread
#pragma unroll
        for (int l = 0; l < 2; ++l) {
            int idx = l * 256 + tid;
            int r = idx >> 2;            // 0..127
            int c = (idx & 3) << 2;      // 0,4,8,12
            float4 av = *(const float4*)(A + (size_t)(bm + r) * K + k0 + c);
            As[c + 0][r] = av.x; As[c + 1][r] = av.y;
            As[c + 2][r] = av.z; As[c + 3][r] = av.w;
            float4 wv = *(const float4*)(W + (size_t)(bn + r) * K + k0 + c);
            Ws[c + 0][r] = wv.x; Ws[c + 1][r] = wv.y;
            Ws[c + 2][r] = wv.z; Ws[c + 3][r] = wv.w;
        }
        __syncthreads();

#pragma unroll
        for (int k = 0; k < TILE_K; ++k) {
            float4 a0 = *(const float4*)&As[k][ty * 4];
            float4 a1 = *(const float4*)&As[k][ty * 4 + 64];
            float4 b0 = *(const float4*)&Ws[k][tx * 4];
            float4 b1 = *(const float4*)&Ws[k][tx * 4 + 64];
            float ar[2][4] = {{a0.x, a0.y, a0.z, a0.w}, {a1.x, a1.y, a1.z, a1.w}};
            float br[2][4] = {{b0.x, b0.y, b0.z, b0.w}, {b1.x, b1.y, b1.z, b1.w}};
#pragma unroll
            for (int ri = 0; ri < 2; ++ri)
#pragma unroll
                for (int i = 0; i < 4; ++i)
#pragma unroll
                    for (int ci = 0; ci < 2; ++ci)
#pragma unroll
                        for (int j = 0; j < 4; ++j)
                            acc[ri][ci][i][j] += ar[ri][i] * br[ci][j];
        }
        __syncthreads();
    }

    // epilogue: add bias, store float4
#pragma unroll
    for (int ri = 0; ri < 2; ++ri) {
#pragma unroll
        for (int i = 0; i < 4; ++i) {
            int row = bm + ri * 64 + ty * 4 + i;
#pragma unroll
            for (int ci = 0; ci < 2; ++ci) {
                int col = bn + ci * 64 + tx * 4;
                float4 bv = *(const float4*)(bias + col);
                float4 ov;
                ov.x = acc[ri][ci][i][0] + bv.x;
                ov.y = acc[ri][ci][i][1] + bv.y;
                ov.z = acc[ri][ci][i][2] + bv.z;
                ov.w = acc[ri][ci][i][3] + bv.w;
                *(float4*)(out + (size_t)row * N + col) = ov;
            }
        }
    }
}

// ---------------------------------------------------------------------------
// Local (banded) attention, window = 128, hd = 64.
// One block per (head, 64-query tile). 5 key-chunks of 64.
// S = Q@K^T as 64x64x64 register-tiled GEMM; online softmax (m,l per row,
// rows spread over 16 lanes -> shfl_xor 1/2/4/8); P reuses the K LDS buffer;
// then O += P@V. Finite sentinel -3e38 (never -inf) keeps rescale NaN-free.
// LDS: 3 * 64*68*4 = 51 KB -> 3 blocks/CU.
// ---------------------------------------------------------------------------
#define WINDOW_SZ 128

__global__ __launch_bounds__(256) void local_attn(
    const float* __restrict__ qkv,  // [N, 2304]; row = [q(12*64) | k | v]
    float* __restrict__ out,        // [N, 768]
    int N)
{
    const int C  = 768;
    const int C3 = 2304;
    __shared__ __align__(16) float Qt[64][68];   // Qt[d][r]
    __shared__ __align__(16) float KtP[64][68];  // Kt[d][c], reused as P[c][r]
    __shared__ __align__(16) float Vs[64][68];   // Vs[j][d]

    const int tid = threadIdx.x;
    const int tx = tid & 15;
    const int ty = tid >> 4;
    const int ntiles = N >> 6;
    const int h  = blockIdx.x / ntiles;
    const int i0 = (blockIdx.x % ntiles) << 6;
    const int qoff = h * 64;
    const int koff = 768 + h * 64;
    const int voff = 1536 + h * 64;

    // stage Q tile transposed (once per block)
#pragma unroll
    for (int l = 0; l < 4; ++l) {
        int idx = l * 256 + tid;
        int r = idx >> 4;
        int d = (idx & 15) << 2;
        float4 v = *(const float4*)(qkv + (size_t)(i0 + r) * C3 + qoff + d);
        Qt[d + 0][r] = v.x; Qt[d + 1][r] = v.y;
        Qt[d + 2][r] = v.z; Qt[d + 3][r] = v.w;
    }

    float mrow[4], lrow[4], oacc[4][4];
#pragma unroll
    for (int i = 0; i < 4; ++i) {
        mrow[i] = -3.0e38f;
        lrow[i] = 0.f;
#pragma unroll
        for (int j = 0; j < 4; ++j) oacc[i][j] = 0.f;
    }

    for (int ch = 0; ch < 5; ++ch) {
        int jbase = i0 - 128 + ch * 64;
        if (jbase < 0 || jbase >= N) continue;   // chunks are 64-aligned: all-or-nothing

        __syncthreads();  // previous chunk's P/V reads done before overwrite
        // stage K (transposed) and V chunks
#pragma unroll
        for (int l = 0; l < 4; ++l) {
            int idx = l * 256 + tid;
            int r = idx >> 4;
            int d = (idx & 15) << 2;
            float4 kv = *(const float4*)(qkv + (size_t)(jbase + r) * C3 + koff + d);
            KtP[d + 0][r] = kv.x; KtP[d + 1][r] = kv.y;
            KtP[d + 2][r] = kv.z; KtP[d + 3][r] = kv.w;
            float4 vv = *(const float4*)(qkv + (size_t)(jbase + r) * C3 + voff + d);
            *(float4*)&Vs[r][d] = vv;
        }
        __syncthreads();

        // S = Q @ K^T  (64x64, reduce over d=64)
        float s[4][4];
#pragma unroll
        for (int i = 0; i < 4; ++i)
#pragma unroll
            for (int j = 0; j < 4; ++j) s[i][j] = 0.f;
#pragma unroll
        for (int d = 0; d < 64; ++d) {
            float4 qv = *(const float4*)&Qt[d][ty * 4];
            float4 kv = *(const float4*)&KtP[d][tx * 4];
            float qr[4] = {qv.x, qv.y, qv.z, qv.w};
            float kr[4] = {kv.x, kv.y, kv.z, kv.w};
#pragma unroll
            for (int i = 0; i < 4; ++i)
#pragma unroll
                for (int j = 0; j < 4; ++j)
                    s[i][j] += qr[i] * kr[j];
        }
        __syncthreads();  // all K reads done; KtP now reusable for P

        // mask + scale + online softmax; write P into KtP as P[col][row]
#pragma unroll
        for (int i = 0; i < 4; ++i) {
            int gi = i0 + ty * 4 + i;
            float rmax = -3.0e38f;
#pragma unroll
            for (int j = 0; j < 4; ++j) {
                int gj = jbase + tx * 4 + j;
                int dist = gi - gj; if (dist < 0) dist = -dist;
                float sv = (dist <= WINDOW_SZ) ? s[i][j] * 0.125f : -3.0e38f;
                s[i][j] = sv;
                rmax = fmaxf(rmax, sv);
            }
            rmax = fmaxf(rmax, __shfl_xor(rmax, 1));
            rmax = fmaxf(rmax, __shfl_xor(rmax, 2));
            rmax = fmaxf(rmax, __shfl_xor(rmax, 4));
            rmax = fmaxf(rmax, __shfl_xor(rmax, 8));
            float mn = fmaxf(mrow[i], rmax);
            float al = expf(mrow[i] - mn);   // first chunk: exp(-3e38) = 0
            float rs = 0.f;
#pragma unroll
            for (int j = 0; j < 4; ++j) {
                float pv = expf(s[i][j] - mn);   // masked: exp(-3e38) = 0
                KtP[tx * 4 + j][ty * 4 + i] = pv;
                rs += pv;
            }
            rs += __shfl_xor(rs, 1); rs += __shfl_xor(rs, 2);
            rs += __shfl_xor(rs, 4); rs += __shfl_xor(rs, 8);
            lrow[i] = lrow[i] * al + rs;
            mrow[i] = mn;
#pragma unroll
            for (int j = 0; j < 4; ++j) oacc[i][j] *= al;
        }
        __syncthreads();

        // O += P @ V  (reduce over 64 keys)
#pragma unroll
        for (int jj = 0; jj < 64; ++jj) {
            float4 pv = *(const float4*)&KtP[jj][ty * 4];
            float4 vv = *(const float4*)&Vs[jj][tx * 4];
            float pr[4] = {pv.x, pv.y, pv.z, pv.w};
            float vr[4] = {vv.x, vv.y, vv.z, vv.w};
#pragma unroll
            for (int i = 0; i < 4; ++i)
#pragma unroll
                for (int j = 0; j < 4; ++j)
                    oacc[i][j] += pr[i] * vr[j];
        }
    }

    // epilogue: normalize and store
#pragma unroll
    for (int i = 0; i < 4; ++i) {
        int row = i0 + ty * 4 + i;
        float inv = 1.0f / lrow[i];
        float4 ov;
        ov.x = oacc[i][0] * inv;
        ov.y = oacc[i][1] * inv;
        ov.z = oacc[i][2] * inv;
        ov.w = oacc[i][3] * inv;
        *(float4*)(out + (size_t)row * C + qoff + tx * 4) = ov;
    }
}

// ---------------------------------------------------------------------------
extern "C" void kernel_launch(void* const* d_in, const int* in_sizes, int n_in,
                              void* d_out, int out_size, void* d_ws, size_t ws_size,
                              hipStream_t stream) {
    (void)n_in; (void)out_size; (void)ws_size;
    const float* x      = (const float*)d_in[0];
    const float* qkv_w  = (const float*)d_in[1];
    const float* qkv_b  = (const float*)d_in[2];
    const float* proj_w = (const float*)d_in[3];
    const float* proj_b = (const float*)d_in[4];
    float* outp = (float*)d_out;

    const int C    = in_sizes[2] / 3;     // 768
    const int Nseq = in_sizes[0] / C;     // 4096
    const int C3   = 3 * C;               // 2304

    float* qkv  = (float*)d_ws;                       // [Nseq, C3]  37.75 MB
    float* attn = qkv + (size_t)Nseq * C3;            // [Nseq, C]   12.6 MB

    dim3 blk(256);
    // qkv = x @ qkv_w^T + qkv_b
    gemm_bias_nt<<<dim3(C3 / TILE_N, Nseq / TILE_M), blk, 0, stream>>>(
        x, qkv_w, qkv_b, qkv, Nseq, C3, C);
    // banded attention per head
    local_attn<<<dim3((C / 64) * (Nseq / 64)), blk, 0, stream>>>(qkv, attn, Nseq);
    // out = attn @ proj_w^T + proj_b
    gemm_bias_nt<<<dim3(C / TILE_N, Nseq / TILE_M), blk, 0, stream>>>(
        attn, proj_w, proj_b, outp, Nseq, C, C);
}

// Round 2
// 454.632 us; speedup vs baseline: 1.2629x; 1.2629x over previous
//
#include <hip/hip_runtime.h>
#include <cmath>

// ---------------------------------------------------------------------------
// GEMM: out[M,N] = A[M,K] @ W[N,K]^T + bias[N]   (torch Linear, NT layout)
// 128x128 tile, BK=16, 256 threads, 8x8 per thread as 2x2 quadrants of 4x4.
// (unchanged from R1 — optimize after attention is fixed)
// ---------------------------------------------------------------------------
#define TILE_M 128
#define TILE_N 128
#define TILE_K 16

__global__ __launch_bounds__(256) void gemm_bias_nt(
    const float* __restrict__ A,
    const float* __restrict__ W,
    const float* __restrict__ bias,
    float* __restrict__ out,
    int M, int N, int K)
{
    __shared__ __align__(16) float As[TILE_K][TILE_M + 4];
    __shared__ __align__(16) float Ws[TILE_K][TILE_N + 4];

    const int tid = threadIdx.x;
    const int tx = tid & 15;   // col group
    const int ty = tid >> 4;   // row group
    const int bm = blockIdx.y * TILE_M;
    const int bn = blockIdx.x * TILE_N;

    float acc[2][2][4][4];
#pragma unroll
    for (int a = 0; a < 2; ++a)
#pragma unroll
        for (int b = 0; b < 2; ++b)
#pragma unroll
            for (int i = 0; i < 4; ++i)
#pragma unroll
                for (int j = 0; j < 4; ++j)
                    acc[a][b][i][j] = 0.f;

    for (int k0 = 0; k0 < K; k0 += TILE_K) {
#pragma unroll
        for (int l = 0; l < 2; ++l) {
            int idx = l * 256 + tid;
            int r = idx >> 2;
            int c = (idx & 3) << 2;
            float4 av = *(const float4*)(A + (size_t)(bm + r) * K + k0 + c);
            As[c + 0][r] = av.x; As[c + 1][r] = av.y;
            As[c + 2][r] = av.z; As[c + 3][r] = av.w;
            float4 wv = *(const float4*)(W + (size_t)(bn + r) * K + k0 + c);
            Ws[c + 0][r] = wv.x; Ws[c + 1][r] = wv.y;
            Ws[c + 2][r] = wv.z; Ws[c + 3][r] = wv.w;
        }
        __syncthreads();

#pragma unroll
        for (int k = 0; k < TILE_K; ++k) {
            float4 a0 = *(const float4*)&As[k][ty * 4];
            float4 a1 = *(const float4*)&As[k][ty * 4 + 64];
            float4 b0 = *(const float4*)&Ws[k][tx * 4];
            float4 b1 = *(const float4*)&Ws[k][tx * 4 + 64];
            float ar[2][4] = {{a0.x, a0.y, a0.z, a0.w}, {a1.x, a1.y, a1.z, a1.w}};
            float br[2][4] = {{b0.x, b0.y, b0.z, b0.w}, {b1.x, b1.y, b1.z, b1.w}};
#pragma unroll
            for (int ri = 0; ri < 2; ++ri)
#pragma unroll
                for (int i = 0; i < 4; ++i)
#pragma unroll
                    for (int ci = 0; ci < 2; ++ci)
#pragma unroll
                        for (int j = 0; j < 4; ++j)
                            acc[ri][ci][i][j] += ar[ri][i] * br[ci][j];
        }
        __syncthreads();
    }

#pragma unroll
    for (int ri = 0; ri < 2; ++ri) {
#pragma unroll
        for (int i = 0; i < 4; ++i) {
            int row = bm + ri * 64 + ty * 4 + i;
#pragma unroll
            for (int ci = 0; ci < 2; ++ci) {
                int col = bn + ci * 64 + tx * 4;
                float4 bv = *(const float4*)(bias + col);
                float4 ov;
                ov.x = acc[ri][ci][i][0] + bv.x;
                ov.y = acc[ri][ci][i][1] + bv.y;
                ov.z = acc[ri][ci][i][2] + bv.z;
                ov.w = acc[ri][ci][i][3] + bv.w;
                *(float4*)(out + (size_t)row * N + col) = ov;
            }
        }
    }
}

// ---------------------------------------------------------------------------
// Local (banded) attention, window = 128, hd = 64.
// One block per (head, 64-query tile), 5 key-chunks of 64.
// ALL tiles row-major [row][d] (stride 68) — no transpose writes.
// Thread (ty=tid>>4, tx=tid&15) owns rows ty*4+i, cols tx+16*j.
//   - S: per-thread dot4 over d (Q read broadcast, K read ~2-way)
//   - P scalar writes: bank = (16ty+4i+tx+16j)%32 -> exactly 2-way (free)
//   - PV: P rows read as b128 broadcast, V rows b128 contiguous
// Unrolls capped at 4; __launch_bounds__(256,3) caps VGPR (no spills).
// LDS: 3 * 64*68*4 = 51 KB -> 3 blocks/CU.
// ---------------------------------------------------------------------------
#define WINDOW_SZ 128

__global__ __launch_bounds__(256, 3) void local_attn(
    const float* __restrict__ qkv,  // [N, 2304]; row = [q(12*64) | k | v]
    float* __restrict__ out,        // [N, 768]
    int N)
{
    const int C  = 768;
    const int C3 = 2304;
    __shared__ __align__(16) float Qs[64][68];   // Q[r][d]
    __shared__ __align__(16) float KPs[64][68];  // K[c][d], reused as P[r][c]
    __shared__ __align__(16) float Vs[64][68];   // V[c][d]

    const int tid = threadIdx.x;
    const int tx = tid & 15;
    const int ty = tid >> 4;   // 0..15
    const int ntiles = N >> 6;
    const int h  = blockIdx.x / ntiles;
    const int i0 = (blockIdx.x % ntiles) << 6;
    const int qoff = h * 64;
    const int koff = 768 + h * 64;
    const int voff = 1536 + h * 64;

    // stage Q tile row-major (once per block); coalesced, conflict-free
#pragma unroll
    for (int l = 0; l < 4; ++l) {
        int idx = l * 256 + tid;
        int r = idx >> 4;
        int d0 = (idx & 15) << 2;
        *(float4*)&Qs[r][d0] =
            *(const float4*)(qkv + (size_t)(i0 + r) * C3 + qoff + d0);
    }

    float mrow[4], lrow[4], oacc[4][4];
#pragma unroll
    for (int i = 0; i < 4; ++i) {
        mrow[i] = -1.0e30f;
        lrow[i] = 0.f;
#pragma unroll
        for (int j = 0; j < 4; ++j) oacc[i][j] = 0.f;
    }

    for (int ch = 0; ch < 5; ++ch) {
        int jbase = i0 - 128 + ch * 64;
        if (jbase < 0 || jbase >= N) continue;   // chunks are 64-aligned

        __syncthreads();  // prev chunk's P/V reads done before overwrite
#pragma unroll
        for (int l = 0; l < 4; ++l) {
            int idx = l * 256 + tid;
            int r = idx >> 4;
            int d0 = (idx & 15) << 2;
            *(float4*)&KPs[r][d0] =
                *(const float4*)(qkv + (size_t)(jbase + r) * C3 + koff + d0);
            *(float4*)&Vs[r][d0] =
                *(const float4*)(qkv + (size_t)(jbase + r) * C3 + voff + d0);
        }
        __syncthreads();

        // S[i][j] = sum_d Q[ty*4+i][d] * K[tx+16j][d]
        float s[4][4];
#pragma unroll
        for (int i = 0; i < 4; ++i)
#pragma unroll
            for (int j = 0; j < 4; ++j) s[i][j] = 0.f;

#pragma unroll 4
        for (int d0 = 0; d0 < 64; d0 += 4) {
            float4 q4[4], k4[4];
#pragma unroll
            for (int i = 0; i < 4; ++i) q4[i] = *(const float4*)&Qs[ty * 4 + i][d0];
#pragma unroll
            for (int j = 0; j < 4; ++j) k4[j] = *(const float4*)&KPs[tx + 16 * j][d0];
#pragma unroll
            for (int i = 0; i < 4; ++i)
#pragma unroll
                for (int j = 0; j < 4; ++j) {
                    s[i][j] += q4[i].x * k4[j].x + q4[i].y * k4[j].y
                             + q4[i].z * k4[j].z + q4[i].w * k4[j].w;
                }
        }
        __syncthreads();  // K reads done; KPs now reusable as P

        // mask + scale + online softmax; write P row-major into KPs
#pragma unroll
        for (int i = 0; i < 4; ++i) {
            int gi = i0 + ty * 4 + i;
            float rmax = -3.0e38f;
#pragma unroll
            for (int j = 0; j < 4; ++j) {
                int gj = jbase + tx + 16 * j;
                int dist = gi - gj; if (dist < 0) dist = -dist;
                float sv = (dist <= WINDOW_SZ) ? s[i][j] * 0.125f : -3.0e38f;
                s[i][j] = sv;
                rmax = fmaxf(rmax, sv);
            }
            rmax = fmaxf(rmax, __shfl_xor(rmax, 1));
            rmax = fmaxf(rmax, __shfl_xor(rmax, 2));
            rmax = fmaxf(rmax, __shfl_xor(rmax, 4));
            rmax = fmaxf(rmax, __shfl_xor(rmax, 8));
            float mn = fmaxf(mrow[i], rmax);
            float al = __expf(mrow[i] - mn);
            float rs = 0.f;
#pragma unroll
            for (int j = 0; j < 4; ++j) {
                float pv = __expf(s[i][j] - mn);   // masked -> 0
                KPs[ty * 4 + i][tx + 16 * j] = pv; // 2-way banks: free
                rs += pv;
            }
            rs += __shfl_xor(rs, 1); rs += __shfl_xor(rs, 2);
            rs += __shfl_xor(rs, 4); rs += __shfl_xor(rs, 8);
            lrow[i] = lrow[i] * al + rs;
            mrow[i] = mn;
#pragma unroll
            for (int j = 0; j < 4; ++j) oacc[i][j] *= al;
        }
        __syncthreads();

        // O[i][d] += sum_c P[ty*4+i][c] * V[c][tx*4+d]
#pragma unroll 4
        for (int c0 = 0; c0 < 64; c0 += 4) {
            float4 pr[4], vr[4];
#pragma unroll
            for (int i = 0; i < 4; ++i) pr[i] = *(const float4*)&KPs[ty * 4 + i][c0];
#pragma unroll
            for (int jj = 0; jj < 4; ++jj) vr[jj] = *(const float4*)&Vs[c0 + jj][tx * 4];
#pragma unroll
            for (int i = 0; i < 4; ++i) {
                float pv[4] = {pr[i].x, pr[i].y, pr[i].z, pr[i].w};
#pragma unroll
                for (int jj = 0; jj < 4; ++jj) {
                    oacc[i][0] += pv[jj] * vr[jj].x;
                    oacc[i][1] += pv[jj] * vr[jj].y;
                    oacc[i][2] += pv[jj] * vr[jj].z;
                    oacc[i][3] += pv[jj] * vr[jj].w;
                }
            }
        }
    }

    // epilogue: normalize and store
#pragma unroll
    for (int i = 0; i < 4; ++i) {
        int row = i0 + ty * 4 + i;
        float inv = 1.0f / lrow[i];
        float4 ov;
        ov.x = oacc[i][0] * inv;
        ov.y = oacc[i][1] * inv;
        ov.z = oacc[i][2] * inv;
        ov.w = oacc[i][3] * inv;
        *(float4*)(out + (size_t)row * C + qoff + tx * 4) = ov;
    }
}

// ---------------------------------------------------------------------------
extern "C" void kernel_launch(void* const* d_in, const int* in_sizes, int n_in,
                              void* d_out, int out_size, void* d_ws, size_t ws_size,
                              hipStream_t stream) {
    (void)n_in; (void)out_size; (void)ws_size;
    const float* x      = (const float*)d_in[0];
    const float* qkv_w  = (const float*)d_in[1];
    const float* qkv_b  = (const float*)d_in[2];
    const float* proj_w = (const float*)d_in[3];
    const float* proj_b = (const float*)d_in[4];
    float* outp = (float*)d_out;

    const int C    = in_sizes[2] / 3;     // 768
    const int Nseq = in_sizes[0] / C;     // 4096
    const int C3   = 3 * C;               // 2304

    float* qkv  = (float*)d_ws;                       // [Nseq, C3]
    float* attn = qkv + (size_t)Nseq * C3;            // [Nseq, C]

    dim3 blk(256);
    gemm_bias_nt<<<dim3(C3 / TILE_N, Nseq / TILE_M), blk, 0, stream>>>(
        x, qkv_w, qkv_b, qkv, Nseq, C3, C);
    local_attn<<<dim3((C / 64) * (Nseq / 64)), blk, 0, stream>>>(qkv, attn, Nseq);
    gemm_bias_nt<<<dim3(C / TILE_N, Nseq / TILE_M), blk, 0, stream>>>(
        attn, proj_w, proj_b, outp, Nseq, C, C);
}

// Round 3
// 216.186 us; speedup vs baseline: 2.6559x; 2.1030x over previous
//
#include <hip/hip_runtime.h>
#include <hip/hip_fp16.h>
#include <cmath>

typedef _Float16 f16;
typedef __attribute__((ext_vector_type(8))) _Float16 f16x8;
typedef __attribute__((ext_vector_type(4))) _Float16 f16x4;
typedef __attribute__((ext_vector_type(4))) float f32x4;

// async 16B global->LDS (wave-uniform LDS base; HW scatters lane*16)
typedef __attribute__((address_space(3))) unsigned int lds_u32;
typedef const __attribute__((address_space(1))) unsigned int g_u32;
__device__ __forceinline__ void async_copy16(const void* g, void* l) {
    __builtin_amdgcn_global_load_lds((g_u32*)g, (lds_u32*)l, 16, 0, 0);
}

// ---------------------------------------------------------------------------
// f32 -> f16 cast, 4 elems/thread
// ---------------------------------------------------------------------------
__global__ void cast_f32_f16(const float* __restrict__ in, f16* __restrict__ out, int n4) {
    int i = blockIdx.x * blockDim.x + threadIdx.x;
    if (i < n4) {
        float4 v = ((const float4*)in)[i];
        f16x4 o = { (f16)v.x, (f16)v.y, (f16)v.z, (f16)v.w };
        ((f16x4*)out)[i] = o;
    }
}

// ---------------------------------------------------------------------------
// MFMA f16 GEMM: out[M,N] = A[M,K] @ W[N,K]^T + bias[N], fp32 accumulate.
// Block 256 = 4 waves (2x2), tile 128x128, BK=32.
// LDS is fragment-ready: chunk c (16 rows x 32 k) stored as 64 lanes x 16B
// in exact mfma A/B operand order -> global_load_lds dwordx4 staging and
// conflict-free lane-linear ds_read_b128 frag loads.
// A-frag: lane holds A[m=lane&15][k=(lane>>4)*8+j]; B mirrors with W rows.
// C/D: col=lane&15, row=(lane>>4)*4+reg  (dtype-independent, verified).
// ---------------------------------------------------------------------------
#define BM 128
#define BN 128
#define BK 32

__global__ __launch_bounds__(256) void gemm_f16_nt(
    const f16* __restrict__ A,      // [M,K]
    const f16* __restrict__ W,      // [N,K]
    const float* __restrict__ bias, // [N]
    float* __restrict__ out,        // [M,N]
    int M, int N, int K)
{
    __shared__ f16 Ash[8 * 512];   // 8 chunks x (64 lanes x 8 f16)
    __shared__ f16 Bsh[8 * 512];

    const int tid  = threadIdx.x;
    const int lane = tid & 63;
    const int w    = tid >> 6;        // wave 0..3
    const int wr   = w >> 1;          // wave row (0..1)
    const int wc   = w & 1;           // wave col (0..1)
    const int bm   = blockIdx.y * BM;
    const int bn   = blockIdx.x * BN;

    const int lr = lane & 15;         // row/col within 16-tile
    const int lq = lane >> 4;         // k-quad (0..3)

    // staging: wave w owns A chunks {2w,2w+1} and B chunks {2w,2w+1}
    const f16* ga0 = A + (size_t)(bm + (2 * w + 0) * 16 + lr) * K + lq * 8;
    const f16* ga1 = A + (size_t)(bm + (2 * w + 1) * 16 + lr) * K + lq * 8;
    const f16* gb0 = W + (size_t)(bn + (2 * w + 0) * 16 + lr) * K + lq * 8;
    const f16* gb1 = W + (size_t)(bn + (2 * w + 1) * 16 + lr) * K + lq * 8;
    f16* la0 = &Ash[(2 * w + 0) * 512];
    f16* la1 = &Ash[(2 * w + 1) * 512];
    f16* lb0 = &Bsh[(2 * w + 0) * 512];
    f16* lb1 = &Bsh[(2 * w + 1) * 512];

    f32x4 acc[4][4] = {};

    for (int k0 = 0; k0 < K; k0 += BK) {
        __syncthreads();   // prev iter's frag reads done before overwrite
        async_copy16(ga0 + k0, la0);
        async_copy16(ga1 + k0, la1);
        async_copy16(gb0 + k0, lb0);
        async_copy16(gb1 + k0, lb1);
        __syncthreads();   // staging visible (drains vmcnt)

        f16x8 af[4], bf[4];
#pragma unroll
        for (int mt = 0; mt < 4; ++mt)
            af[mt] = *(const f16x8*)&Ash[(wr * 4 + mt) * 512 + lane * 8];
#pragma unroll
        for (int nt = 0; nt < 4; ++nt)
            bf[nt] = *(const f16x8*)&Bsh[(wc * 4 + nt) * 512 + lane * 8];
#pragma unroll
        for (int mt = 0; mt < 4; ++mt)
#pragma unroll
            for (int nt = 0; nt < 4; ++nt)
                acc[mt][nt] = __builtin_amdgcn_mfma_f32_16x16x32_f16(
                    af[mt], bf[nt], acc[mt][nt], 0, 0, 0);
    }

    // epilogue: bias + store
    const int orow = bm + wr * 64 + lq * 4;
    const int ocol = bn + wc * 64 + lr;
#pragma unroll
    for (int nt = 0; nt < 4; ++nt) {
        float bv = bias[ocol + nt * 16];
#pragma unroll
        for (int mt = 0; mt < 4; ++mt)
#pragma unroll
            for (int r = 0; r < 4; ++r)
                out[(size_t)(orow + mt * 16 + r) * N + ocol + nt * 16] =
                    acc[mt][nt][r] + bv;
    }
}

// ---------------------------------------------------------------------------
// Local (banded) attention, window = 128, hd = 64. (R2 structure, f16 out)
// ---------------------------------------------------------------------------
#define WINDOW_SZ 128

__global__ __launch_bounds__(256, 3) void local_attn(
    const float* __restrict__ qkv,  // [N, 2304]; row = [q(12*64) | k | v]
    f16* __restrict__ out,          // [N, 768] f16
    int N)
{
    const int C  = 768;
    const int C3 = 2304;
    __shared__ __align__(16) float Qs[64][68];
    __shared__ __align__(16) float KPs[64][68];
    __shared__ __align__(16) float Vs[64][68];

    const int tid = threadIdx.x;
    const int tx = tid & 15;
    const int ty = tid >> 4;
    const int ntiles = N >> 6;
    const int h  = blockIdx.x / ntiles;
    const int i0 = (blockIdx.x % ntiles) << 6;
    const int qoff = h * 64;
    const int koff = 768 + h * 64;
    const int voff = 1536 + h * 64;

#pragma unroll
    for (int l = 0; l < 4; ++l) {
        int idx = l * 256 + tid;
        int r = idx >> 4;
        int d0 = (idx & 15) << 2;
        *(float4*)&Qs[r][d0] =
            *(const float4*)(qkv + (size_t)(i0 + r) * C3 + qoff + d0);
    }

    float mrow[4], lrow[4], oacc[4][4];
#pragma unroll
    for (int i = 0; i < 4; ++i) {
        mrow[i] = -1.0e30f;
        lrow[i] = 0.f;
#pragma unroll
        for (int j = 0; j < 4; ++j) oacc[i][j] = 0.f;
    }

    for (int ch = 0; ch < 5; ++ch) {
        int jbase = i0 - 128 + ch * 64;
        if (jbase < 0 || jbase >= N) continue;

        __syncthreads();
#pragma unroll
        for (int l = 0; l < 4; ++l) {
            int idx = l * 256 + tid;
            int r = idx >> 4;
            int d0 = (idx & 15) << 2;
            *(float4*)&KPs[r][d0] =
                *(const float4*)(qkv + (size_t)(jbase + r) * C3 + koff + d0);
            *(float4*)&Vs[r][d0] =
                *(const float4*)(qkv + (size_t)(jbase + r) * C3 + voff + d0);
        }
        __syncthreads();

        float s[4][4];
#pragma unroll
        for (int i = 0; i < 4; ++i)
#pragma unroll
            for (int j = 0; j < 4; ++j) s[i][j] = 0.f;

#pragma unroll 4
        for (int d0 = 0; d0 < 64; d0 += 4) {
            float4 q4[4], k4[4];
#pragma unroll
            for (int i = 0; i < 4; ++i) q4[i] = *(const float4*)&Qs[ty * 4 + i][d0];
#pragma unroll
            for (int j = 0; j < 4; ++j) k4[j] = *(const float4*)&KPs[tx + 16 * j][d0];
#pragma unroll
            for (int i = 0; i < 4; ++i)
#pragma unroll
                for (int j = 0; j < 4; ++j) {
                    s[i][j] += q4[i].x * k4[j].x + q4[i].y * k4[j].y
                             + q4[i].z * k4[j].z + q4[i].w * k4[j].w;
                }
        }
        __syncthreads();

#pragma unroll
        for (int i = 0; i < 4; ++i) {
            int gi = i0 + ty * 4 + i;
            float rmax = -3.0e38f;
#pragma unroll
            for (int j = 0; j < 4; ++j) {
                int gj = jbase + tx + 16 * j;
                int dist = gi - gj; if (dist < 0) dist = -dist;
                float sv = (dist <= WINDOW_SZ) ? s[i][j] * 0.125f : -3.0e38f;
                s[i][j] = sv;
                rmax = fmaxf(rmax, sv);
            }
            rmax = fmaxf(rmax, __shfl_xor(rmax, 1));
            rmax = fmaxf(rmax, __shfl_xor(rmax, 2));
            rmax = fmaxf(rmax, __shfl_xor(rmax, 4));
            rmax = fmaxf(rmax, __shfl_xor(rmax, 8));
            float mn = fmaxf(mrow[i], rmax);
            float al = __expf(mrow[i] - mn);
            float rs = 0.f;
#pragma unroll
            for (int j = 0; j < 4; ++j) {
                float pv = __expf(s[i][j] - mn);
                KPs[ty * 4 + i][tx + 16 * j] = pv;
                rs += pv;
            }
            rs += __shfl_xor(rs, 1); rs += __shfl_xor(rs, 2);
            rs += __shfl_xor(rs, 4); rs += __shfl_xor(rs, 8);
            lrow[i] = lrow[i] * al + rs;
            mrow[i] = mn;
#pragma unroll
            for (int j = 0; j < 4; ++j) oacc[i][j] *= al;
        }
        __syncthreads();

#pragma unroll 4
        for (int c0 = 0; c0 < 64; c0 += 4) {
            float4 pr[4], vr[4];
#pragma unroll
            for (int i = 0; i < 4; ++i) pr[i] = *(const float4*)&KPs[ty * 4 + i][c0];
#pragma unroll
            for (int jj = 0; jj < 4; ++jj) vr[jj] = *(const float4*)&Vs[c0 + jj][tx * 4];
#pragma unroll
            for (int i = 0; i < 4; ++i) {
                float pv[4] = {pr[i].x, pr[i].y, pr[i].z, pr[i].w};
#pragma unroll
                for (int jj = 0; jj < 4; ++jj) {
                    oacc[i][0] += pv[jj] * vr[jj].x;
                    oacc[i][1] += pv[jj] * vr[jj].y;
                    oacc[i][2] += pv[jj] * vr[jj].z;
                    oacc[i][3] += pv[jj] * vr[jj].w;
                }
            }
        }
    }

#pragma unroll
    for (int i = 0; i < 4; ++i) {
        int row = i0 + ty * 4 + i;
        float inv = 1.0f / lrow[i];
        f16x4 ov = { (f16)(oacc[i][0] * inv), (f16)(oacc[i][1] * inv),
                     (f16)(oacc[i][2] * inv), (f16)(oacc[i][3] * inv) };
        *(f16x4*)(out + (size_t)row * C + qoff + tx * 4) = ov;
    }
}

// ---------------------------------------------------------------------------
extern "C" void kernel_launch(void* const* d_in, const int* in_sizes, int n_in,
                              void* d_out, int out_size, void* d_ws, size_t ws_size,
                              hipStream_t stream) {
    (void)n_in; (void)out_size; (void)ws_size;
    const float* x      = (const float*)d_in[0];
    const float* qkv_w  = (const float*)d_in[1];
    const float* qkv_b  = (const float*)d_in[2];
    const float* proj_w = (const float*)d_in[3];
    const float* proj_b = (const float*)d_in[4];
    float* outp = (float*)d_out;

    const int C    = in_sizes[2] / 3;     // 768
    const int Nseq = in_sizes[0] / C;     // 4096
    const int C3   = 3 * C;               // 2304

    char* ws = (char*)d_ws;
    float* qkv = (float*)ws;            ws += (size_t)Nseq * C3 * 4;   // 37.75 MB
    f16* xh    = (f16*)ws;              ws += (size_t)Nseq * C * 2;    // 6.3 MB (reused as attn_h)
    f16* wh_q  = (f16*)ws;              ws += (size_t)C3 * C * 2;      // 3.5 MB
    f16* wh_p  = (f16*)ws;                                             // 1.2 MB
    f16* attn_h = xh;   // alias: xh dead after GEMM1, attn written after

    dim3 blk(256);
    // casts
    {
        int n4 = Nseq * C / 4;
        cast_f32_f16<<<dim3((n4 + 255) / 256), blk, 0, stream>>>(x, xh, n4);
        n4 = C3 * C / 4;
        cast_f32_f16<<<dim3((n4 + 255) / 256), blk, 0, stream>>>(qkv_w, wh_q, n4);
        n4 = C * C / 4;
        cast_f32_f16<<<dim3((n4 + 255) / 256), blk, 0, stream>>>(proj_w, wh_p, n4);
    }
    // qkv = x @ qkv_w^T + qkv_b   (f16 MFMA, fp32 acc)
    gemm_f16_nt<<<dim3(C3 / BN, Nseq / BM), blk, 0, stream>>>(
        xh, wh_q, qkv_b, qkv, Nseq, C3, C);
    // banded attention per head -> f16
    local_attn<<<dim3((C / 64) * (Nseq / 64)), blk, 0, stream>>>(qkv, attn_h, Nseq);
    // out = attn @ proj_w^T + proj_b
    gemm_f16_nt<<<dim3(C / BN, Nseq / BM), blk, 0, stream>>>(
        attn_h, wh_p, proj_b, outp, Nseq, C, C);
}

// Round 4
// 166.031 us; speedup vs baseline: 3.4582x; 1.3021x over previous
//
#include <hip/hip_runtime.h>
#include <hip/hip_fp16.h>
#include <cmath>

typedef _Float16 f16;
typedef __attribute__((ext_vector_type(8))) _Float16 f16x8;
typedef __attribute__((ext_vector_type(4))) _Float16 f16x4;
typedef __attribute__((ext_vector_type(4))) float f32x4;

// async 16B global->LDS (per-lane global gather; LDS dest = base + lane*16)
typedef __attribute__((address_space(3))) unsigned int lds_u32;
typedef const __attribute__((address_space(1))) unsigned int g_u32;
__device__ __forceinline__ void async_copy16(const void* g, void* l) {
    __builtin_amdgcn_global_load_lds((g_u32*)g, (lds_u32*)l, 16, 0, 0);
}

// ---------------------------------------------------------------------------
// f32 -> f16 cast, 4 elems/thread
// ---------------------------------------------------------------------------
__global__ void cast_f32_f16(const float* __restrict__ in, f16* __restrict__ out, int n4) {
    int i = blockIdx.x * blockDim.x + threadIdx.x;
    if (i < n4) {
        float4 v = ((const float4*)in)[i];
        f16x4 o = { (f16)v.x, (f16)v.y, (f16)v.z, (f16)v.w };
        ((f16x4*)out)[i] = o;
    }
}

// ---------------------------------------------------------------------------
// MFMA f16 GEMM: out[M,N] = A[M,K] @ W[N,K]^T + bias[N], fp32 accumulate.
// Templated output type (f16 for qkv intermediate, float for final out).
// 128x128 tile, BK=32, 4 waves; frag-ready LDS + global_load_lds width=16.
// ---------------------------------------------------------------------------
#define BM 128
#define BN 128
#define BK 32

template <typename OT>
__global__ __launch_bounds__(256) void gemm_f16_nt(
    const f16* __restrict__ A,      // [M,K]
    const f16* __restrict__ W,      // [N,K]
    const float* __restrict__ bias, // [N]
    OT* __restrict__ out,           // [M,N]
    int M, int N, int K)
{
    __shared__ f16 Ash[8 * 512];
    __shared__ f16 Bsh[8 * 512];

    const int tid  = threadIdx.x;
    const int lane = tid & 63;
    const int w    = tid >> 6;
    const int wr   = w >> 1;
    const int wc   = w & 1;
    const int bm   = blockIdx.y * BM;
    const int bn   = blockIdx.x * BN;

    const int lr = lane & 15;
    const int lq = lane >> 4;

    const f16* ga0 = A + (size_t)(bm + (2 * w + 0) * 16 + lr) * K + lq * 8;
    const f16* ga1 = A + (size_t)(bm + (2 * w + 1) * 16 + lr) * K + lq * 8;
    const f16* gb0 = W + (size_t)(bn + (2 * w + 0) * 16 + lr) * K + lq * 8;
    const f16* gb1 = W + (size_t)(bn + (2 * w + 1) * 16 + lr) * K + lq * 8;
    f16* la0 = &Ash[(2 * w + 0) * 512];
    f16* la1 = &Ash[(2 * w + 1) * 512];
    f16* lb0 = &Bsh[(2 * w + 0) * 512];
    f16* lb1 = &Bsh[(2 * w + 1) * 512];

    f32x4 acc[4][4] = {};

    for (int k0 = 0; k0 < K; k0 += BK) {
        __syncthreads();
        async_copy16(ga0 + k0, la0);
        async_copy16(ga1 + k0, la1);
        async_copy16(gb0 + k0, lb0);
        async_copy16(gb1 + k0, lb1);
        __syncthreads();

        f16x8 af[4], bf[4];
#pragma unroll
        for (int mt = 0; mt < 4; ++mt)
            af[mt] = *(const f16x8*)&Ash[(wr * 4 + mt) * 512 + lane * 8];
#pragma unroll
        for (int nt = 0; nt < 4; ++nt)
            bf[nt] = *(const f16x8*)&Bsh[(wc * 4 + nt) * 512 + lane * 8];
#pragma unroll
        for (int mt = 0; mt < 4; ++mt)
#pragma unroll
            for (int nt = 0; nt < 4; ++nt)
                acc[mt][nt] = __builtin_amdgcn_mfma_f32_16x16x32_f16(
                    af[mt], bf[nt], acc[mt][nt], 0, 0, 0);
    }

    const int orow = bm + wr * 64 + lq * 4;
    const int ocol = bn + wc * 64 + lr;
#pragma unroll
    for (int nt = 0; nt < 4; ++nt) {
        float bv = bias[ocol + nt * 16];
#pragma unroll
        for (int mt = 0; mt < 4; ++mt)
#pragma unroll
            for (int r = 0; r < 4; ++r)
                out[(size_t)(orow + mt * 16 + r) * N + ocol + nt * 16] =
                    (OT)(acc[mt][nt][r] + bv);
    }
}

// ---------------------------------------------------------------------------
// MFMA local attention, window=128, hd=64. qkv f16 [N][2304], out f16 [N][768].
// Block = (head, 64-query tile), 4 waves; wave w owns query rows w*16..+15.
// Per 64-key chunk: S via mfma (Q A-frags in regs, K B-frags from LDS via
// global_load_lds), online softmax in C-layout regs, P->LDS (swizzled A-frag
// layout, per-wave so no barrier), PV via mfma with XOR-swizzled Vt.
// Swizzles (derived conflict-free for both write & read):
//   Vt: element (c,d) at d*64 + (((c>>3)^(d>>3)^d)&7)*8 + (c&7)
//   Ps: chunk l' stored at l' ^ ((l'>>3)&7)
// LDS = 8+8+8 = 24 KB.
// ---------------------------------------------------------------------------
#define WINDOW_SZ 128

__global__ __launch_bounds__(256) void local_attn_mfma(
    const f16* __restrict__ qkv,  // [N, 2304] f16: [q(12*64)|k|v]
    f16* __restrict__ out,        // [N, 768] f16
    int N)
{
    const int C  = 768;
    const int C3 = 2304;
    __shared__ f16 Ks[8 * 512];   // B-frag segs (nc, ks)
    __shared__ f16 Vt[4096];      // swizzled V^T
    __shared__ f16 Ps[8 * 512];   // A-frag segs (w, cs)

    const int tid  = threadIdx.x;
    const int lane = tid & 63;
    const int w    = tid >> 6;
    const int r15  = lane & 15;
    const int q4   = lane >> 4;
    const int ntiles = N >> 6;
    const int h  = blockIdx.x / ntiles;
    const int i0 = (blockIdx.x % ntiles) << 6;
    const int qoff = h * 64;
    const int koff = 768 + h * 64;
    const int voff = 1536 + h * 64;

    // Q A-frags direct from global (loop-invariant)
    f16x8 qf[2];
    {
        const f16* qrow = qkv + (size_t)(i0 + w * 16 + r15) * C3 + qoff + q4 * 8;
        qf[0] = *(const f16x8*)(qrow);
        qf[1] = *(const f16x8*)(qrow + 32);
    }

    const int vc0 = tid >> 3;           // V-staging: row c (rep adds 32)
    const int vd0 = (tid & 7) * 8;      // d-chunk
    const int va  = vd0 >> 3;

    f32x4 o[4] = {};
    float m_r[4], l_r[4];
#pragma unroll
    for (int r = 0; r < 4; ++r) { m_r[r] = -1.0e30f; l_r[r] = 0.f; }

    for (int ch = 0; ch < 5; ++ch) {
        int jbase = i0 - 128 + ch * 64;
        if (jbase < 0 || jbase >= N) continue;
        bool need_mask = (ch == 0) || (ch == 4);

        __syncthreads();   // prior chunk's Ks/Vt reads done
        // K -> Ks: wave w stages segs (nc=w, ks=0/1)
        {
            const f16* kr = qkv + (size_t)(jbase + w * 16 + r15) * C3 + koff + q4 * 8;
            async_copy16(kr,      &Ks[(w * 2 + 0) * 512]);
            async_copy16(kr + 32, &Ks[(w * 2 + 1) * 512]);
        }
        // V -> Vt swizzled transpose (conflict-free writes)
#pragma unroll
        for (int rep = 0; rep < 2; ++rep) {
            int c = vc0 + rep * 32;
            f16x8 v = *(const f16x8*)(qkv + (size_t)(jbase + c) * C3 + voff + vd0);
            int cc = c >> 3, c7 = c & 7;
#pragma unroll
            for (int j = 0; j < 8; ++j) {
                int d = vd0 + j;
                int x = (cc ^ va ^ j) & 7;
                Vt[d * 64 + x * 8 + c7] = v[j];
            }
        }
        __syncthreads();   // staging visible (drains vmcnt + lds)

        // S = Q @ K^T : C-tiles s[nt], cols nt*16+r15, rows w*16+q4*4+r
        f32x4 s[4] = {};
#pragma unroll
        for (int ks = 0; ks < 2; ++ks)
#pragma unroll
            for (int nt = 0; nt < 4; ++nt) {
                f16x8 kf = *(const f16x8*)&Ks[(nt * 2 + ks) * 512 + lane * 8];
                s[nt] = __builtin_amdgcn_mfma_f32_16x16x32_f16(qf[ks], kf, s[nt], 0, 0, 0);
            }

        // scale + mask
        const int rowg = i0 + w * 16 + q4 * 4;
#pragma unroll
        for (int nt = 0; nt < 4; ++nt)
#pragma unroll
            for (int r = 0; r < 4; ++r) {
                float sv = s[nt][r] * 0.125f;
                if (need_mask) {
                    int dist = (rowg + r) - (jbase + nt * 16 + r15);
                    if (dist < 0) dist = -dist;
                    if (dist > WINDOW_SZ) sv = -3.0e38f;
                }
                s[nt][r] = sv;
            }

        // online softmax per row r (reduce across 16 lanes of the quad)
        float al[4];
#pragma unroll
        for (int r = 0; r < 4; ++r) {
            float rmax = fmaxf(fmaxf(s[0][r], s[1][r]), fmaxf(s[2][r], s[3][r]));
            rmax = fmaxf(rmax, __shfl_xor(rmax, 1));
            rmax = fmaxf(rmax, __shfl_xor(rmax, 2));
            rmax = fmaxf(rmax, __shfl_xor(rmax, 4));
            rmax = fmaxf(rmax, __shfl_xor(rmax, 8));
            float mn = fmaxf(m_r[r], rmax);
            al[r] = __expf(m_r[r] - mn);
            m_r[r] = mn;
            float rs = 0.f;
#pragma unroll
            for (int nt = 0; nt < 4; ++nt) {
                float pv = __expf(s[nt][r] - mn);
                s[nt][r] = pv;
                rs += pv;
            }
            rs += __shfl_xor(rs, 1); rs += __shfl_xor(rs, 2);
            rs += __shfl_xor(rs, 4); rs += __shfl_xor(rs, 8);
            l_r[r] = l_r[r] * al[r] + rs;
        }

        // P -> Ps (A-frag segs, swizzled; per-wave buffer, no barrier needed)
#pragma unroll
        for (int nt = 0; nt < 4; ++nt) {
            int cs = nt >> 1;
            int lp_hi = 16 * ((nt & 1) * 2 + (r15 >> 3));
#pragma unroll
            for (int r = 0; r < 4; ++r) {
                int lp  = (q4 * 4 + r) + lp_hi;
                int lpp = lp ^ ((lp >> 3) & 7);
                Ps[(w * 2 + cs) * 512 + lpp * 8 + (lane & 7)] = (f16)s[nt][r];
            }
        }
        // rescale O
#pragma unroll
        for (int nd = 0; nd < 4; ++nd)
#pragma unroll
            for (int r = 0; r < 4; ++r) o[nd][r] *= al[r];

        // O += P @ V
#pragma unroll
        for (int cs = 0; cs < 2; ++cs) {
            int lpp = lane ^ ((lane >> 3) & 7);
            f16x8 pf = *(const f16x8*)&Ps[(w * 2 + cs) * 512 + lpp * 8];
#pragma unroll
            for (int nd = 0; nd < 4; ++nd) {
                int d = nd * 16 + r15;
                int x = ((cs * 4 + q4) ^ (d >> 3) ^ d) & 7;
                f16x8 vf = *(const f16x8*)&Vt[d * 64 + x * 8];
                o[nd] = __builtin_amdgcn_mfma_f32_16x16x32_f16(pf, vf, o[nd], 0, 0, 0);
            }
        }
    }

    // epilogue: normalize, store f16
    float inv[4];
#pragma unroll
    for (int r = 0; r < 4; ++r) inv[r] = 1.0f / l_r[r];
#pragma unroll
    for (int nd = 0; nd < 4; ++nd)
#pragma unroll
        for (int r = 0; r < 4; ++r) {
            int row = i0 + w * 16 + q4 * 4 + r;
            out[(size_t)row * C + qoff + nd * 16 + r15] = (f16)(o[nd][r] * inv[r]);
        }
}

// ---------------------------------------------------------------------------
extern "C" void kernel_launch(void* const* d_in, const int* in_sizes, int n_in,
                              void* d_out, int out_size, void* d_ws, size_t ws_size,
                              hipStream_t stream) {
    (void)n_in; (void)out_size; (void)ws_size;
    const float* x      = (const float*)d_in[0];
    const float* qkv_w  = (const float*)d_in[1];
    const float* qkv_b  = (const float*)d_in[2];
    const float* proj_w = (const float*)d_in[3];
    const float* proj_b = (const float*)d_in[4];
    float* outp = (float*)d_out;

    const int C    = in_sizes[2] / 3;     // 768
    const int Nseq = in_sizes[0] / C;     // 4096
    const int C3   = 3 * C;               // 2304

    char* ws = (char*)d_ws;
    f16* qkv_h = (f16*)ws;   ws += (size_t)Nseq * C3 * 2;   // 18.9 MB
    f16* xh    = (f16*)ws;   ws += (size_t)Nseq * C * 2;    // 6.3 MB (reused as attn_h)
    f16* wh_q  = (f16*)ws;   ws += (size_t)C3 * C * 2;      // 3.5 MB
    f16* wh_p  = (f16*)ws;                                   // 1.2 MB
    f16* attn_h = xh;   // alias: xh dead after GEMM1

    dim3 blk(256);
    {
        int n4 = Nseq * C / 4;
        cast_f32_f16<<<dim3((n4 + 255) / 256), blk, 0, stream>>>(x, xh, n4);
        n4 = C3 * C / 4;
        cast_f32_f16<<<dim3((n4 + 255) / 256), blk, 0, stream>>>(qkv_w, wh_q, n4);
        n4 = C * C / 4;
        cast_f32_f16<<<dim3((n4 + 255) / 256), blk, 0, stream>>>(proj_w, wh_p, n4);
    }
    // qkv (f16) = x @ qkv_w^T + qkv_b
    gemm_f16_nt<f16><<<dim3(C3 / BN, Nseq / BM), blk, 0, stream>>>(
        xh, wh_q, qkv_b, qkv_h, Nseq, C3, C);
    // banded attention -> f16
    local_attn_mfma<<<dim3((C / 64) * (Nseq / 64)), blk, 0, stream>>>(
        qkv_h, attn_h, Nseq);
    // out (f32) = attn @ proj_w^T + proj_b
    gemm_f16_nt<float><<<dim3(C / BN, Nseq / BM), blk, 0, stream>>>(
        attn_h, wh_p, proj_b, outp, Nseq, C, C);
}